// Round 7
// baseline (11015.662 us; speedup 1.0000x reference)
//
#include <hip/hip_runtime.h>

// DeepLSTM on MI355X — persistent kernel (208 blocks, co-resident), relaxed-atomic grid
// barrier, weights persistent in VGPR/AGPR, depth-4 software-pipelined K-loop with raw
// s_barrier (lgkm-only).
// ROUND 7: per-XCD h mirror. A 4-block team per XCD (elected via XCC_ID + ticket)
// copies h1/h2 slabs from L3 (sc1) into an XCD-local mirror (normal stores -> own L2)
// each superstep; workers read the mirror with plain cached loads after buffer_inv sc0
// (L1-only invalidate). Cross-fabric h traffic drops 44MB -> ~4MB per step.
// Mirror aliases Wih1/Whh1 staging (only written after all weight preloads: s>=1).

typedef __attribute__((ext_vector_type(8))) short short8;
typedef __attribute__((ext_vector_type(16))) float f32x16;
typedef __attribute__((ext_vector_type(4))) float f32x4;

#define Tn 256
#define In 256
#define Hn 1024
#define On 256
#define SP 136            // LDS act row stride (elems): 272B rows, 16B-aligned
#define NL1 64
#define NL2 128
#define NY  16
#define NBLK (NL1 + NL2 + NY)   // 208
#define CHUNK_B 17408
#define SMEM_SZ 55808
#define BHe 65536
#define MSLOT 131072      // elems per mirror slot: h1 (65536) + h2 (65536)

// d_ws layout
#define WS_WIH1 0
#define WS_WHH1 2097152
#define WS_WIH2 10485760
#define WS_WHH2 20971520
#define WS_WL   29360128
#define WS_X    30015488
#define WS_H1   38404096
#define WS_H2   38666240
#define WS_ARR  38928384
#define WS_IMPR (WS_ARR + 1024)   // 32 ints: per-(xcd,slice) import flags
#define WS_TICK (WS_ARR + 1152)   // 8 ints: per-xcd election tickets

#define WAIT_LGKM0() __builtin_amdgcn_s_waitcnt(0xC07F)
#define RAW_BARRIER() do { \
    WAIT_LGKM0(); \
    __builtin_amdgcn_sched_barrier(0); \
    __builtin_amdgcn_s_barrier(); \
    __builtin_amdgcn_sched_barrier(0); \
  } while (0)

static __device__ __forceinline__ unsigned short f2b(float f) {
  union { float f; unsigned int i; } v; v.f = f;
  unsigned int u = v.i;
  return (unsigned short)((u + 0x7FFFu + ((u >> 16) & 1u)) >> 16);  // RNE
}
static __device__ __forceinline__ float sigm(float x) { return 1.0f / (1.0f + __expf(-x)); }
static __device__ __forceinline__ float tanhf_(float x) {
  float ax = fabsf(x);
  float e = __expf(-2.0f * ax);
  return copysignf((1.0f - e) / (1.0f + e), x);
}
static __device__ __forceinline__ unsigned long long ld64a(const void* p) {
  return __hip_atomic_load((const unsigned long long*)p, __ATOMIC_RELAXED, __HIP_MEMORY_SCOPE_AGENT);
}
static __device__ __forceinline__ void st32a(void* p, unsigned int v) {
  __hip_atomic_store((unsigned int*)p, v, __ATOMIC_RELAXED, __HIP_MEMORY_SCOPE_AGENT);
}
static __device__ __forceinline__ void st64a(void* p, unsigned long long v) {
  __hip_atomic_store((unsigned long long*)p, v, __ATOMIC_RELAXED, __HIP_MEMORY_SCOPE_AGENT);
}
static __device__ __forceinline__ int ld32a_i(const int* p) {
  return __hip_atomic_load(p, __ATOMIC_RELAXED, __HIP_MEMORY_SCOPE_AGENT);
}

static __device__ __forceinline__ void grid_barrier(int* arrive, int bid, int tid,
                                                    int lane, int tgt) {
  __syncthreads();   // drains vmcnt(0): all sc1 h-stores complete before publish
  if (tid == 0)
    __hip_atomic_store(&arrive[bid], tgt, __ATOMIC_RELAXED, __HIP_MEMORY_SCOPE_AGENT);
  if (tid < 64) {
    bool done = false;
    while (!done) {
      bool ok = true;
      #pragma unroll
      for (int j = 0; j < 4; ++j) {
        int idx = lane + j * 64;
        if (idx < NBLK) {
          int v = ld32a_i(&arrive[idx]);
          ok = ok && (v >= tgt);
        }
      }
      done = __all(ok);
      if (!done) __builtin_amdgcn_s_sleep(1);
    }
  }
  __syncthreads();
}

__global__ void __launch_bounds__(256) cvt_bf16(const float* __restrict__ src,
                                                unsigned short* __restrict__ dst, int n4) {
  int i = blockIdx.x * blockDim.x + threadIdx.x;
  if (i >= n4) return;
  float4 v = ((const float4*)src)[i];
  ushort4 o;
  o.x = f2b(v.x); o.y = f2b(v.y); o.z = f2b(v.z); o.w = f2b(v.w);
  ((ushort4*)dst)[i] = o;
}

__global__ void __launch_bounds__(256) prep_zero(unsigned short* h1buf,
                                                 unsigned short* h2buf,
                                                 int* arrive, int* impr, int* tick) {
  int i = blockIdx.x * blockDim.x + threadIdx.x;
  st64a((unsigned long long*)h1buf + i, 0ull);
  st64a((unsigned long long*)h1buf + 16384 + i, 0ull);
  st64a((unsigned long long*)h2buf + i, 0ull);
  st64a((unsigned long long*)h2buf + 16384 + i, 0ull);
  if (i < 256) st32a(arrive + i, 0u);
  if (i < 32)  st32a(impr + i, 0xFFFFFFFFu);   // -1
  if (i < 8)   st32a(tick + i, 0u);
}

__global__ void __launch_bounds__(256, 1) lstm_persist(
    const unsigned short* __restrict__ x,
    const unsigned short* __restrict__ Wih1, const unsigned short* __restrict__ Whh1,
    const float* __restrict__ bih1, const float* __restrict__ bhh1,
    const unsigned short* __restrict__ Wih2, const unsigned short* __restrict__ Whh2,
    const float* __restrict__ bih2, const float* __restrict__ bhh2,
    const unsigned short* __restrict__ Wl,  const float* __restrict__ bl,
    float* __restrict__ out,
    unsigned short* __restrict__ h1buf, unsigned short* __restrict__ h2buf,
    int* __restrict__ arrive,
    unsigned short* __restrict__ mir, int* __restrict__ imp_ready, int* __restrict__ tick)
{
  extern __shared__ char smem[];
  unsigned short* sbuf0 = (unsigned short*)smem;
  unsigned short* sbuf1 = (unsigned short*)(smem + CHUNK_B);
  float* sG = (float*)(smem + 2 * CHUNK_B);
  float* sc = (float*)(smem + 2 * CHUNK_B + 16896);

  const int tid = threadIdx.x;
  const int bid = blockIdx.x;
  const int lane = tid & 63;
  const int wid = tid >> 6;
  const int srow = tid >> 2;
  const int sseg = tid & 3;

  for (int e = tid; e < 1024; e += 256) sc[e] = 0.0f;

  // ---- XCD identification + import-team election (once) ----
  unsigned int xcc;
  asm volatile("s_getreg_b32 %0, hwreg(HW_REG_XCC_ID)" : "=s"(xcc));
  const int my_xcd = (int)(xcc & 7);
  int* sInt = (int*)sG;
  if (tid == 0) sInt[0] = atomicAdd(&tick[my_xcd], 1);
  __syncthreads();
  const int tk = sInt[0];
  __syncthreads();

  uint4 rs[4][4];                 // depth-4 relay

  // import: copy slice tk of {h1(t-1), h2(t-2)} into mirror slot s&1 (own-XCD L2)
  auto do_import = [&](int s) {
    if (tk < 4 && s >= 1) {
      const unsigned short* isrc = (tk < 2)
          ? h1buf + ((s + 1) & 1) * BHe + (tk & 1) * 32768
          : h2buf + (s & 1) * BHe + (tk & 1) * 32768;
      unsigned short* idst = mir + ((size_t)my_xcd * 2 + (s & 1)) * MSLOT
                             + (tk < 2 ? 0 : 65536) + (tk & 1) * 32768;
      const unsigned long long* s8 = (const unsigned long long*)isrc;
      unsigned long long* d8 = (unsigned long long*)idst;
      #pragma unroll
      for (int k2 = 0; k2 < 32; ++k2)
        d8[tid + k2 * 256] = ld64a(s8 + tid + k2 * 256);
      asm volatile("s_waitcnt vmcnt(0)" ::: "memory");
      st32a(&imp_ready[my_xcd * 4 + tk], (unsigned)s);
    }
  };
  // wait for this superstep's import, then invalidate L1 (not L2!)
  auto poll_binv = [&](int s) {
    if (tid < 64) {
      bool done = false;
      while (!done) {
        int v = (lane < 4) ? ld32a_i(&imp_ready[my_xcd * 4 + lane]) : 0x7fffffff;
        done = __all(v >= s);
        if (!done) __builtin_amdgcn_s_sleep(1);
      }
    }
    __syncthreads();
    asm volatile("buffer_inv sc0" ::: "memory");
  };

  if (bid < NL1) {
    // =================== layer 1 ===================
    const int j0 = bid << 4;
    const int mtile = wid & 1, ntile = wid >> 1;
    const int arow = mtile * 32 + (lane & 31);
    const int brow = ntile * 32 + (lane & 31);
    const int gr = ((brow >> 4) << 10) + j0 + (brow & 15);
    const int hi8 = (lane >> 5) << 3;

    short8 w[80];
    #pragma unroll
    for (int c = 0; c < 10; ++c) {
      const unsigned short* wrow = (c < 2) ? (Wih1 + (size_t)gr * In + c * 128)
                                           : (Whh1 + (size_t)gr * Hn + (c - 2) * 128);
      #pragma unroll
      for (int k8 = 0; k8 < 8; ++k8)
        w[c * 8 + k8] = *(const short8*)(wrow + k8 * 16 + hi8);
    }
    float bs[2][2][4];
    #pragma unroll
    for (int p = 0; p < 2; ++p) {
      int pi = tid + p * 256, op = (pi & 7) << 1;
      #pragma unroll
      for (int k = 0; k < 2; ++k) {
        int o = op + k;
        #pragma unroll
        for (int g = 0; g < 4; ++g)
          bs[p][k][g] = bih1[g * 1024 + j0 + o] + bhh1[g * 1024 + j0 + o];
      }
    }

    for (int s = 0; s <= Tn + 1; ++s) {
      do_import(s);
      if (s < Tn) {
        const int t = s;
        unsigned short* h1wr = h1buf + (t & 1) * BHe;
        f32x16 acc0 = {}, acc1 = {};

        if (s == 0) {
          // h1(-1)=0: only the two x chunks contribute
          #pragma unroll
          for (int cc = 0; cc < 2; ++cc) {
            const uint4* s4 = (const uint4*)(x + ((size_t)srow * Tn + t) * In + cc * 128 + sseg * 32);
            #pragma unroll
            for (int j = 0; j < 4; ++j) rs[cc][j] = s4[j];
          }
          #pragma unroll
          for (int c = 0; c < 2; ++c) {
            unsigned short* buf = (c & 1) ? sbuf1 : sbuf0;
            uint4* d4 = (uint4*)(buf + srow * SP + sseg * 32);
            #pragma unroll
            for (int j = 0; j < 4; ++j) d4[j] = rs[c][j];
            RAW_BARRIER();
            const unsigned short* ab = buf + arow * SP + hi8;
            #pragma unroll
            for (int k8 = 0; k8 < 8; k8 += 2) {
              acc0 = __builtin_amdgcn_mfma_f32_32x32x16_bf16(*(const short8*)(ab + k8 * 16),      w[c * 8 + k8],     acc0, 0, 0, 0);
              acc1 = __builtin_amdgcn_mfma_f32_32x32x16_bf16(*(const short8*)(ab + k8 * 16 + 16), w[c * 8 + k8 + 1], acc1, 0, 0, 0);
            }
          }
          RAW_BARRIER();
        } else {
          poll_binv(s);
          const unsigned short* h1m = mir + ((size_t)my_xcd * 2 + (s & 1)) * MSLOT;  // h1(t-1)
          auto ldc = [&](int cc, int d) {
            const unsigned short* src = (cc < 2)
                ? x + ((size_t)srow * Tn + t) * In + cc * 128
                : h1m + srow * Hn + (cc - 2) * 128;
            const uint4* s4 = (const uint4*)(src + sseg * 32);
            #pragma unroll
            for (int j = 0; j < 4; ++j) rs[d][j] = s4[j];
          };
          ldc(0, 0); ldc(1, 1); ldc(2, 2); ldc(3, 3);
          #pragma unroll
          for (int c = 0; c < 10; ++c) {
            unsigned short* buf = (c & 1) ? sbuf1 : sbuf0;
            uint4* d4 = (uint4*)(buf + srow * SP + sseg * 32);
            #pragma unroll
            for (int j = 0; j < 4; ++j) d4[j] = rs[c & 3][j];
            if (c + 4 < 10) ldc(c + 4, c & 3);
            RAW_BARRIER();
            const unsigned short* ab = buf + arow * SP + hi8;
            #pragma unroll
            for (int k8 = 0; k8 < 8; k8 += 2) {
              acc0 = __builtin_amdgcn_mfma_f32_32x32x16_bf16(*(const short8*)(ab + k8 * 16),      w[c * 8 + k8],     acc0, 0, 0, 0);
              acc1 = __builtin_amdgcn_mfma_f32_32x32x16_bf16(*(const short8*)(ab + k8 * 16 + 16), w[c * 8 + k8 + 1], acc1, 0, 0, 0);
            }
          }
          RAW_BARRIER();
        }

        f32x16 accv = acc0 + acc1;
        #pragma unroll
        for (int i = 0; i < 16; ++i) {  // C/D: col=lane&31, row=(reg&3)+8*(reg>>2)+4*(lane>>5)
          int rm = (i & 3) + ((i >> 2) << 3) + ((lane >> 5) << 2);
          sG[(mtile * 32 + rm) * 65 + brow] = accv[i];
        }
        __syncthreads();
        #pragma unroll
        for (int p = 0; p < 2; ++p) {
          int pi = tid + p * 256;
          int b = pi >> 3, op = (pi & 7) << 1;
          const float* gb = sG + b * 65;
          unsigned int pack = 0;
          #pragma unroll
          for (int k = 0; k < 2; ++k) {
            int o = op + k, e = b * 16 + o;
            float ig = gb[o]      + bs[p][k][0];
            float fg = gb[16 + o] + bs[p][k][1];
            float gg = gb[32 + o] + bs[p][k][2];
            float og = gb[48 + o] + bs[p][k][3];
            float cn = sigm(fg) * sc[e] + sigm(ig) * tanhf_(gg);
            sc[e] = cn;
            pack |= ((unsigned int)f2b(sigm(og) * tanhf_(cn))) << (16 * k);
          }
          st32a(h1wr + b * Hn + j0 + op, pack);
        }
      }
      if (s <= Tn) grid_barrier(arrive, bid, tid, lane, s + 1);
    }

  } else if (bid < NL1 + NL2) {
    // =================== layer 2 ===================
    const int j0 = (bid - NL1) << 3;
    const int mtile = wid & 1, ks = wid >> 1;
    const int arow = mtile * 32 + (lane & 31);
    const int brow = lane & 31;
    const int gr = ((brow >> 3) << 10) + j0 + (brow & 7);
    const int hi8 = (lane >> 5) << 3;

    short8 w[80];
    if (ks == 0) {
      #pragma unroll
      for (int c = 0; c < 10; ++c)
        #pragma unroll
        for (int k8 = 0; k8 < 8; ++k8)
          w[c * 8 + k8] = *(const short8*)(Wih2 + (size_t)gr * 1280 + c * 128 + k8 * 16 + hi8);
    } else {
      #pragma unroll
      for (int c = 0; c < 8; ++c)
        #pragma unroll
        for (int k8 = 0; k8 < 8; ++k8)
          w[c * 8 + k8] = *(const short8*)(Whh2 + (size_t)gr * Hn + c * 128 + k8 * 16 + hi8);
    }
    float bs[2][4];
    {
      int op = (tid & 3) << 1;
      #pragma unroll
      for (int k = 0; k < 2; ++k) {
        int o = op + k;
        #pragma unroll
        for (int g = 0; g < 4; ++g)
          bs[k][g] = bih2[g * 1024 + j0 + o] + bhh2[g * 1024 + j0 + o];
      }
    }

    for (int s = 0; s <= Tn + 1; ++s) {
      do_import(s);
      if (s >= 1 && s <= Tn) {
        const int t = s - 1;
        unsigned short* h2wr = h2buf + (t & 1) * BHe;
        f32x16 acc0 = {}, acc1 = {};

        poll_binv(s);
        const unsigned short* h1m = mir + ((size_t)my_xcd * 2 + (s & 1)) * MSLOT;          // h1(t)
        const unsigned short* h2m = h1m + 65536;                                            // h2(t-1)
        auto ldc = [&](int cc, int d) {
          const unsigned short* src = (cc < 2)
              ? x + ((size_t)srow * Tn + t) * In + cc * 128
              : (cc < 10 ? h1m + srow * Hn + (cc - 2) * 128
                         : h2m + srow * Hn + (cc - 10) * 128);
          const uint4* s4 = (const uint4*)(src + sseg * 32);
          #pragma unroll
          for (int j = 0; j < 4; ++j) rs[d][j] = s4[j];
        };
        ldc(0, 0); ldc(1, 1); ldc(2, 2); ldc(3, 3);
        #pragma unroll
        for (int c = 0; c < 18; ++c) {
          unsigned short* buf = (c & 1) ? sbuf1 : sbuf0;
          uint4* d4 = (uint4*)(buf + srow * SP + sseg * 32);
          #pragma unroll
          for (int j = 0; j < 4; ++j) d4[j] = rs[c & 3][j];
          if (c + 4 < 18) ldc(c + 4, c & 3);
          RAW_BARRIER();
          bool active = (ks == 0) ? (c < 10) : (c >= 10);
          if (active) {
            int ib = ((ks == 0) ? c : (c - 10)) * 8;
            const unsigned short* ab = buf + arow * SP + hi8;
            #pragma unroll
            for (int k8 = 0; k8 < 8; k8 += 2) {
              acc0 = __builtin_amdgcn_mfma_f32_32x32x16_bf16(*(const short8*)(ab + k8 * 16),      w[ib + k8],     acc0, 0, 0, 0);
              acc1 = __builtin_amdgcn_mfma_f32_32x32x16_bf16(*(const short8*)(ab + k8 * 16 + 16), w[ib + k8 + 1], acc1, 0, 0, 0);
            }
          }
        }
        RAW_BARRIER();

        f32x16 accv = acc0 + acc1;
        #pragma unroll
        for (int i = 0; i < 16; ++i) {
          int rm = (i & 3) + ((i >> 2) << 3) + ((lane >> 5) << 2);
          sG[ks * 2112 + (mtile * 32 + rm) * 33 + brow] = accv[i];
        }
        __syncthreads();
        {
          int b = tid >> 2, op = (tid & 3) << 1;
          const float* g0 = sG + b * 33;
          const float* g1 = sG + 2112 + b * 33;
          unsigned int pack = 0;
          #pragma unroll
          for (int k = 0; k < 2; ++k) {
            int o = op + k, e = b * 8 + o;
            float ig = g0[o]      + g1[o]      + bs[k][0];
            float fg = g0[8 + o]  + g1[8 + o]  + bs[k][1];
            float gg = g0[16 + o] + g1[16 + o] + bs[k][2];
            float og = g0[24 + o] + g1[24 + o] + bs[k][3];
            float cn = sigm(fg) * sc[e] + sigm(ig) * tanhf_(gg);
            sc[e] = cn;
            pack |= ((unsigned int)f2b(sigm(og) * tanhf_(cn))) << (16 * k);
          }
          st32a(h2wr + b * Hn + j0 + op, pack);
        }
      }
      if (s <= Tn) grid_barrier(arrive, bid, tid, lane, s + 1);
    }

  } else {
    // =================== head ===================
    const int o0 = (bid - NL1 - NL2) << 4;
    const int quad = lane >> 4;
    const int l15 = lane & 15;
    const int hi8y = quad << 3;

    short8 wy[40];
    #pragma unroll
    for (int c = 0; c < 10; ++c)
      #pragma unroll
      for (int q = 0; q < 4; ++q)
        wy[c * 4 + q] = *(const short8*)(Wl + (size_t)(o0 + l15) * 1280 + c * 128 + q * 32 + hi8y);
    const float blv = bl[o0 + l15];

    for (int s = 0; s <= Tn + 1; ++s) {
      do_import(s);
      if (s >= 2) {
        const int t = s - 2;
        f32x4 acc0 = {}, acc1 = {};

        poll_binv(s);
        const unsigned short* h2m = mir + ((size_t)my_xcd * 2 + (s & 1)) * MSLOT + 65536;  // h2(t)
        auto ldc = [&](int cc, int d) {
          const unsigned short* src = (cc < 2)
              ? x + ((size_t)srow * Tn + t) * In + cc * 128
              : h2m + srow * Hn + (cc - 2) * 128;
          const uint4* s4 = (const uint4*)(src + sseg * 32);
          #pragma unroll
          for (int j = 0; j < 4; ++j) rs[d][j] = s4[j];
        };
        ldc(0, 0); ldc(1, 1); ldc(2, 2); ldc(3, 3);
        #pragma unroll
        for (int c = 0; c < 10; ++c) {
          unsigned short* buf = (c & 1) ? sbuf1 : sbuf0;
          uint4* d4 = (uint4*)(buf + srow * SP + sseg * 32);
          #pragma unroll
          for (int j = 0; j < 4; ++j) d4[j] = rs[c & 3][j];
          if (c + 4 < 10) ldc(c + 4, c & 3);
          RAW_BARRIER();
          const unsigned short* ab = buf + (wid * 16 + l15) * SP + hi8y;
          acc0 = __builtin_amdgcn_mfma_f32_16x16x32_bf16(*(const short8*)(ab),      wy[c * 4 + 0], acc0, 0, 0, 0);
          acc1 = __builtin_amdgcn_mfma_f32_16x16x32_bf16(*(const short8*)(ab + 32), wy[c * 4 + 1], acc1, 0, 0, 0);
          acc0 = __builtin_amdgcn_mfma_f32_16x16x32_bf16(*(const short8*)(ab + 64), wy[c * 4 + 2], acc0, 0, 0, 0);
          acc1 = __builtin_amdgcn_mfma_f32_16x16x32_bf16(*(const short8*)(ab + 96), wy[c * 4 + 3], acc1, 0, 0, 0);
        }
        RAW_BARRIER();

        f32x4 accv = acc0 + acc1;
        #pragma unroll
        for (int i = 0; i < 4; ++i) {   // C/D 16x16: col=lane&15, row=(lane>>4)*4+reg
          int b = wid * 16 + quad * 4 + i;
          out[((size_t)b * Tn + t) * On + o0 + l15] = accv[i] + blv;
        }
      }
      if (s <= Tn) grid_barrier(arrive, bid, tid, lane, s + 1);
    }
  }
}

extern "C" void kernel_launch(void* const* d_in, const int* in_sizes, int n_in,
                              void* d_out, int out_size, void* d_ws, size_t ws_size,
                              hipStream_t stream) {
  (void)in_sizes; (void)n_in; (void)out_size; (void)ws_size;
  const float* xf    = (const float*)d_in[0];
  const float* Wih1f = (const float*)d_in[1];
  const float* Whh1f = (const float*)d_in[2];
  const float* bih1  = (const float*)d_in[3];
  const float* bhh1  = (const float*)d_in[4];
  const float* Wih2f = (const float*)d_in[5];
  const float* Whh2f = (const float*)d_in[6];
  const float* bih2  = (const float*)d_in[7];
  const float* bhh2  = (const float*)d_in[8];
  const float* Wlf   = (const float*)d_in[9];
  const float* bl    = (const float*)d_in[10];
  float* out = (float*)d_out;

  char* ws = (char*)d_ws;
  unsigned short* Wih1b = (unsigned short*)(ws + WS_WIH1);
  unsigned short* Whh1b = (unsigned short*)(ws + WS_WHH1);
  unsigned short* Wih2b = (unsigned short*)(ws + WS_WIH2);
  unsigned short* Whh2b = (unsigned short*)(ws + WS_WHH2);
  unsigned short* Wlb   = (unsigned short*)(ws + WS_WL);
  unsigned short* xb    = (unsigned short*)(ws + WS_X);
  unsigned short* h1buf = (unsigned short*)(ws + WS_H1);
  unsigned short* h2buf = (unsigned short*)(ws + WS_H2);
  int* arrive           = (int*)(ws + WS_ARR);
  unsigned short* mir   = (unsigned short*)(ws + WS_WIH1);  // aliases Wih1b/Whh1b (safe: written only after preload)
  int* imp_ready        = (int*)(ws + WS_IMPR);
  int* tick             = (int*)(ws + WS_TICK);

  hipLaunchKernelGGL(cvt_bf16, dim3(1024), dim3(256), 0, stream, Wih1f, Wih1b, 262144);
  hipLaunchKernelGGL(cvt_bf16, dim3(4096), dim3(256), 0, stream, Whh1f, Whh1b, 1048576);
  hipLaunchKernelGGL(cvt_bf16, dim3(5120), dim3(256), 0, stream, Wih2f, Wih2b, 1310720);
  hipLaunchKernelGGL(cvt_bf16, dim3(4096), dim3(256), 0, stream, Whh2f, Whh2b, 1048576);
  hipLaunchKernelGGL(cvt_bf16, dim3(320),  dim3(256), 0, stream, Wlf,   Wlb,   81920);
  hipLaunchKernelGGL(cvt_bf16, dim3(4096), dim3(256), 0, stream, xf,    xb,    1048576);

  hipLaunchKernelGGL(prep_zero, dim3(64), dim3(256), 0, stream, h1buf, h2buf, arrive, imp_ready, tick);

  hipLaunchKernelGGL(lstm_persist, dim3(NBLK), dim3(256), SMEM_SZ, stream,
                     xb, Wih1b, Whh1b, bih1, bhh1, Wih2b, Whh2b, bih2, bhh2, Wlb, bl,
                     out, h1buf, h2buf, arrive, mir, imp_ready, tick);
}